// Round 10
// baseline (1603.947 us; speedup 1.0000x reference)
//
#include <hip/hip_runtime.h>
#include <math.h>

#define N_USERS 100000
#define N_ITEMS 50000
#define NR      150000
#define N_EDGES 2000000
#define D       64
#define EPS     1e-12f

#define NCHUNK 8        // coarse chunks == XCDs
#define UCH 12500       // users per coarse chunk
#define ICH 6250        // items per coarse chunk
#define FCH_U 64        // user rows per fine chunk  (LDS acc 16 KB)
#define FCH_I 32        // item rows per fine chunk  (LDS acc 8 KB)
#define NFINE 196       // fine chunks per coarse chunk (ceil(12500/64)=ceil(6250/32)=196)
#define NFTOT (NCHUNK*NFINE)   // 1568

#define CSEG 262144     // coarse segment capacity (mean 250K, +26 sigma)
#define FSEG 1600       // fine segment capacity  (mean 1280, +9 sigma)
#define OVF_CAP 4096

#define EPT 8
#define PA_BLOCKS ((N_EDGES + 256*EPT - 1) / (256*EPT))   // 977
#define PREP_BLOCKS ((NR + 3) / 4)                         // 37500
#define PB_PER 128
#define PB_BLOCKS (NCHUNK * PB_PER)                        // 1024

// ---------------- workspace layout (bytes) ----------------
// scal  : float4[NR]           @ 0            2,400,000
// xh    : ushort[NR*64] (z!)   @ 2,400,000   19,200,000
// cpart : u32[8*CSEG]          @ 21,600,000   8,388,608
// fpart : u32[NFTOT*FSEG]      @ 29,988,608  10,035,200
// ccurU : int[8]               @ 40,023,808          32
// ccurI : int[8]               @ 40,023,840          32
// fcurU : int[NFTOT]           @ 40,023,872       6,272
// fcurI : int[NFTOT]           @ 40,030,144       6,272
// ovfc  : int (+pad)           @ 40,036,416           8
// ovf   : int2[OVF_CAP]        @ 40,036,424      32,768
#define SCAL_OFF  0u
#define XH_OFF    2400000u
#define CPART_OFF 21600000u
#define FPART_OFF 29988608u
#define CCURU_OFF 40023808u
#define CCURI_OFF 40023840u
#define FCURU_OFF 40023872u
#define FCURI_OFF 40030144u
#define OVFC_OFF  40036416u
#define OVF_OFF   40036424u
#define CTR_OFF   CCURU_OFF
#define CTR_LEN   (OVFC_OFF + 8u - CCURU_OFF)     // one memset covers all ctrs
#define WS_NEW    (OVF_OFF + 8u * OVF_CAP)

__device__ __forceinline__ unsigned short f2bf(float v) {
    unsigned int b = __float_as_uint(v);
    b += 0x7FFFu + ((b >> 16) & 1u);              // RNE
    return (unsigned short)(b >> 16);
}
#define BF_LO(w) __uint_as_float((w) << 16)
#define BF_HI(w) __uint_as_float((w) & 0xFFFF0000u)

// ---------------------------------------------------------------------------
// Fused: coarse partition side-0 (blocks [0,PA_BLOCKS)) + prep (rest).
// Both are pure streams (no cache-resident hot set) -> safe to co-schedule.
// prep:  xh[r] = bf16(z_r) with z = x*invn ;  scal[r]={invn, rsd, beta, rsd*norm}
// partA: LDS 8-bin histogram -> 1 global atomic per (block,bin) -> burst scatter
// ---------------------------------------------------------------------------
template<int SIDE>
__device__ __forceinline__ void partA_body(const int* __restrict__ u,
                                           const int* __restrict__ i,
                                           int* __restrict__ ccur,
                                           unsigned int* __restrict__ cpart,
                                           int* __restrict__ ovfc,
                                           int2* __restrict__ ovf,
                                           int blk) {
    __shared__ int h[NCHUNK];
    __shared__ int base[NCHUNK];
    int tid = threadIdx.x;
    int e0  = blk * (256 * EPT);
    if (tid < NCHUNK) h[tid] = 0;
    __syncthreads();

    int bins[EPT]; unsigned int vals[EPT];
    #pragma unroll
    for (int k = 0; k < EPT; ++k) {
        int e = e0 + k * 256 + tid;
        bool ok = (e < N_EDGES);
        int uu = ok ? __builtin_nontemporal_load(u + e) : 0;
        int ii = ok ? __builtin_nontemporal_load(i + e) : 0;
        int bin, loc; unsigned int val;
        if (SIDE == 0) { bin = uu / UCH; loc = uu - bin * UCH;
                         val = ((unsigned)loc << 16) | (unsigned)ii; }
        else           { bin = ii / ICH; loc = ii - bin * ICH;
                         val = ((unsigned)loc << 17) | (unsigned)uu; }
        bins[k] = ok ? bin : -1; vals[k] = val;
        if (ok) atomicAdd(&h[bin], 1);
    }
    __syncthreads();
    if (tid < NCHUNK) { base[tid] = atomicAdd(&ccur[tid], h[tid]); h[tid] = 0; }
    __syncthreads();

    #pragma unroll
    for (int k = 0; k < EPT; ++k) {
        int b = bins[k];
        if (b >= 0) {
            int r   = atomicAdd(&h[b], 1);
            int off = base[b] + r;
            if (off < CSEG) {
                cpart[(size_t)b * CSEG + off] = vals[k];
            } else {
                int pp = atomicAdd(ovfc, 1);
                if (pp < OVF_CAP) {
                    int own, nbr;
                    if (SIDE == 0) { own = b * UCH + (int)(vals[k] >> 16);
                                     nbr = N_USERS + (int)(vals[k] & 0xFFFF); }
                    else           { own = N_USERS + b * ICH + (int)(vals[k] >> 17);
                                     nbr = (int)(vals[k] & 0x1FFFF); }
                    ovf[pp] = make_int2(own, nbr);
                }
            }
        }
    }
}

__global__ void prep_partA0_kernel(const float* __restrict__ x,
                                   const float* __restrict__ beta,
                                   const float* __restrict__ du,
                                   const float* __restrict__ di,
                                   float4* __restrict__ scal,
                                   unsigned short* __restrict__ xh,
                                   const int* __restrict__ u,
                                   const int* __restrict__ i,
                                   int* __restrict__ ccurU,
                                   unsigned int* __restrict__ cpart,
                                   int* __restrict__ ovfc,
                                   int2* __restrict__ ovf) {
    if (blockIdx.x < PA_BLOCKS) {
        partA_body<0>(u, i, ccurU, cpart, ovfc, ovf, blockIdx.x);
        return;
    }
    int b    = blockIdx.x - PA_BLOCKS;
    int gid  = b * blockDim.x + threadIdx.x;
    int r    = gid >> 6;
    int lane = gid & 63;
    if (r >= NR) return;

    float v  = x[r * D + lane];
    float ss = v * v;
    #pragma unroll
    for (int m = 32; m >= 1; m >>= 1) ss += __shfl_xor(ss, m);

    float nrm  = fmaxf(sqrtf(ss), EPS);
    float invn = 1.0f / nrm;
    xh[r * D + lane] = f2bf(v * invn);                 // pre-scaled z

    if (lane == 0) {
        float deg = (r < N_USERS) ? du[r] : di[r - N_USERS];
        float bb  = (r < N_USERS) ? beta[r] : 0.0f;
        float rsd = rsqrtf(deg);
        scal[r] = make_float4(invn, rsd, bb, rsd * nrm);   // .w = c = rsd*norm
    }
}

template<int SIDE>
__global__ void partA_kernel(const int* __restrict__ u,
                             const int* __restrict__ i,
                             int* __restrict__ ccur,
                             unsigned int* __restrict__ cpart,
                             int* __restrict__ ovfc,
                             int2* __restrict__ ovf) {
    partA_body<SIDE>(u, i, ccur, cpart, ovfc, ovf, blockIdx.x);
}

// ---------------------------------------------------------------------------
// Fine partition: chunk p (= blockIdx%8, XCD-local) splits its coarse segment
// into 196 fine segments. Stream ~1 MB + fine region ~1.25 MB both fit the
// XCD's private 4 MB L2 -> dirty lines evict ~once.
// ---------------------------------------------------------------------------
template<int SIDE>
__global__ void partB_kernel(const unsigned int* __restrict__ cpart,
                             const int* __restrict__ ccur,
                             int* __restrict__ fcur,
                             unsigned int* __restrict__ fpart,
                             int* __restrict__ ovfc,
                             int2* __restrict__ ovf) {
    __shared__ int h[NFINE];
    __shared__ int base[NFINE];
    const int FCH = (SIDE == 0) ? FCH_U : FCH_I;

    int p   = blockIdx.x & (NCHUNK - 1);
    int jb  = blockIdx.x >> 3;
    int tid = threadIdx.x;
    for (int t = tid; t < NFINE; t += 256) h[t] = 0;
    __syncthreads();

    size_t lo = (size_t)p * CSEG;
    int n = ccur[p]; if (n > CSEG) n = CSEG;

    for (int k = jb * 256 + tid; k < n; k += PB_BLOCKS / NCHUNK * 256) {
        unsigned rec = cpart[lo + k];
        int loc = (SIDE == 0) ? (int)(rec >> 16) : (int)(rec >> 17);
        atomicAdd(&h[loc / FCH], 1);
    }
    __syncthreads();
    for (int t = tid; t < NFINE; t += 256) {
        base[t] = h[t] ? atomicAdd(&fcur[p * NFINE + t], h[t]) : 0;
        h[t] = 0;
    }
    __syncthreads();

    for (int k = jb * 256 + tid; k < n; k += PB_BLOCKS / NCHUNK * 256) {
        unsigned rec = cpart[lo + k];
        int loc = (SIDE == 0) ? (int)(rec >> 16) : (int)(rec >> 17);
        int f = loc / FCH;
        int r = atomicAdd(&h[f], 1);
        int off = base[f] + r;
        if (off < FSEG) {
            fpart[(size_t)(p * NFINE + f) * FSEG + off] = rec;
        } else {
            int pp = atomicAdd(ovfc, 1);
            if (pp < OVF_CAP) {
                int own, nbr;
                if (SIDE == 0) { own = p * UCH + loc; nbr = N_USERS + (int)(rec & 0xFFFF); }
                else           { own = N_USERS + p * ICH + loc; nbr = (int)(rec & 0x1FFFF); }
                ovf[pp] = make_int2(own, nbr);
            }
        }
    }
}

// ---------------------------------------------------------------------------
// Compute: one block per fine chunk. Own-output sub-tile lives in LDS (fp32);
// per-edge: gather z_nbr (128 B) + scal_nbr, 8-lane dot, weight, 8 LDS
// atomicAdds. Final: ONE coalesced write-once of the sub-tile. No global
// atomics, no buckets, no degree caps.
// ---------------------------------------------------------------------------
template<int SIDE>
__global__ void compute_kernel(const unsigned short* __restrict__ xh,
                               const float4* __restrict__ scal,
                               const int* __restrict__ fcur,
                               const unsigned int* __restrict__ fpart,
                               float* __restrict__ out) {
    constexpr int FCH = (SIDE == 0) ? FCH_U : FCH_I;
    __shared__ float acc[FCH * D];

    int p  = blockIdx.x & (NCHUNK - 1);
    int f  = blockIdx.x >> 3;
    int fg = p * NFINE + f;
    int tid = threadIdx.x;
    int g = tid >> 3, q = tid & 7;

    int rows_in_chunk = ((SIDE == 0) ? UCH : ICH) - f * FCH;
    if (rows_in_chunk > FCH) rows_in_chunk = FCH;
    if (rows_in_chunk <= 0) return;
    int row0 = (SIDE == 0) ? (p * UCH + f * FCH) : (N_USERS + p * ICH + f * FCH);

    for (int t = tid; t < rows_in_chunk * D; t += 256) acc[t] = 0.0f;
    __syncthreads();

    int n = fcur[fg]; if (n > FSEG) n = FSEG;
    size_t sb = (size_t)fg * FSEG;

    for (int k = g; k < n; k += 32) {
        unsigned rec = fpart[sb + k];                   // broadcast per group
        int loc, nbr;
        if (SIDE == 0) { loc = (int)(rec >> 16) - f * FCH;
                         nbr = N_USERS + (int)(rec & 0xFFFF); }
        else           { loc = (int)(rec >> 17) - f * FCH;
                         nbr = (int)(rec & 0x1FFFF); }
        int own = row0 + loc;

        float4 so = scal[nbr];
        uint4 ho = *(const uint4*)(xh + (size_t)nbr * D + q * 8);
        uint4 hs = *(const uint4*)(xh + (size_t)own * D + q * 8);   // L1-hot

        float o0 = BF_LO(ho.x), o1 = BF_HI(ho.x);
        float o2 = BF_LO(ho.y), o3 = BF_HI(ho.y);
        float o4 = BF_LO(ho.z), o5 = BF_HI(ho.z);
        float o6 = BF_LO(ho.w), o7 = BF_HI(ho.w);

        float pd = BF_LO(hs.x)*o0 + BF_HI(hs.x)*o1
                 + BF_LO(hs.y)*o2 + BF_HI(hs.y)*o3
                 + BF_LO(hs.z)*o4 + BF_HI(hs.z)*o5
                 + BF_LO(hs.w)*o6 + BF_HI(hs.w)*o7;
        pd += __shfl_xor(pd, 1);
        pd += __shfl_xor(pd, 2);
        pd += __shfl_xor(pd, 4);            // cosine sim (z pre-scaled)

        float bv  = (SIDE == 0) ? scal[own].z : so.z;   // user beta
        float sv  = pd - bv;
        float sig = 1.0f / (1.0f + __expf(-sv));
        float t4  = 4.0f * sig * (1.0f - sig) * so.w;   // * c_nbr = rsd*norm

        float* a = &acc[loc * D + q * 8];
        atomicAdd(&a[0], t4 * o0); atomicAdd(&a[1], t4 * o1);
        atomicAdd(&a[2], t4 * o2); atomicAdd(&a[3], t4 * o3);
        atomicAdd(&a[4], t4 * o4); atomicAdd(&a[5], t4 * o5);
        atomicAdd(&a[6], t4 * o6); atomicAdd(&a[7], t4 * o7);
    }
    __syncthreads();

    for (int t = tid; t < rows_in_chunk * D; t += 256) {
        int lr = t >> 6;
        int row = row0 + lr;
        out[(size_t)row * D + (t & 63)] = acc[t] * scal[row].y;   // * rsd_own
    }
}

// ---------------------------------------------------------------------------
// Overflow fixer: (own_row, nbr_row); recompute in fp32, atomic-add own row.
// ---------------------------------------------------------------------------
__global__ void ovf2_kernel(const float* __restrict__ x,
                            const float4* __restrict__ scal,
                            const int* __restrict__ ovfc,
                            const int2* __restrict__ ovf,
                            float* __restrict__ out) {
    int n = *ovfc;
    if (n > OVF_CAP) n = OVF_CAP;
    int gid  = blockIdx.x * blockDim.x + threadIdx.x;
    int wave = gid >> 6, lane = gid & 63;
    int nw   = (gridDim.x * blockDim.x) >> 6;

    for (int k = wave; k < n; k += nw) {
        int d  = ovf[k].x;
        int nb = ovf[k].y;
        float xd = x[(size_t)d * D + lane];
        float xn = x[(size_t)nb * D + lane];
        float pd = xd * xn;
        #pragma unroll
        for (int m = 32; m >= 1; m >>= 1) pd += __shfl_xor(pd, m);
        float4 sd = scal[d];
        float4 sn = scal[nb];
        float sv  = pd * sd.x * sn.x - (sd.z + sn.z);   // one side has beta=0
        float sig = 1.0f / (1.0f + __expf(-sv));
        float w   = 4.0f * sig * (1.0f - sig) * sd.y * sn.y;
        atomicAdd(&out[(size_t)d * D + lane], w * xn);
    }
}

// ---------------------------------------------------------------------------
// Tier-D fallback (round-1 proven atomics) for small workspace.
// ---------------------------------------------------------------------------
__global__ void norm_kernel(const float* __restrict__ x,
                            float* __restrict__ invn, int nrows) {
    int gid  = blockIdx.x * blockDim.x + threadIdx.x;
    int wave = gid >> 6, lane = gid & 63;
    if (wave >= nrows) return;
    float v  = x[wave * D + lane];
    float ss = v * v;
    #pragma unroll
    for (int m = 32; m >= 1; m >>= 1) ss += __shfl_xor(ss, m);
    if (lane == 0) invn[wave] = 1.0f / fmaxf(sqrtf(ss), EPS);
}

__global__ void edge_kernel(const float* __restrict__ x,
                            const float* __restrict__ beta,
                            const float* __restrict__ du,
                            const float* __restrict__ di,
                            const int* __restrict__ u,
                            const int* __restrict__ i,
                            const float* __restrict__ invn,
                            float* __restrict__ out) {
    int gid  = blockIdx.x * blockDim.x + threadIdx.x;
    int wave = gid >> 6, lane = gid & 63;
    if (wave >= N_EDGES) return;
    int uu = u[wave], ii = i[wave];
    float xu = x[uu * D + lane];
    float xi = x[(N_USERS + ii) * D + lane];
    float p = xu * xi;
    #pragma unroll
    for (int m = 32; m >= 1; m >>= 1) p += __shfl_xor(p, m);
    float s   = p * invn[uu] * invn[N_USERS + ii] - beta[uu];
    float sig = 1.0f / (1.0f + __expf(-s));
    float w   = 4.0f * sig * (1.0f - sig) * rsqrtf(du[uu]) * rsqrtf(di[ii]);
    atomicAdd(&out[uu * D + lane],             w * xi);
    atomicAdd(&out[(N_USERS + ii) * D + lane], w * xu);
}

// ---------------------------------------------------------------------------
extern "C" void kernel_launch(void* const* d_in, const int* in_sizes, int n_in,
                              void* d_out, int out_size, void* d_ws, size_t ws_size,
                              hipStream_t stream) {
    const float* x    = (const float*)d_in[0];
    const float* beta = (const float*)d_in[1];
    const float* du   = (const float*)d_in[2];
    const float* di   = (const float*)d_in[3];
    const int*   u    = (const int*)d_in[4];
    const int*   i    = (const int*)d_in[5];
    float* out = (float*)d_out;
    char*  ws  = (char*)d_ws;

    if (ws_size >= (size_t)WS_NEW) {
        float4*         scal  = (float4*)(ws + SCAL_OFF);
        unsigned short* xh    = (unsigned short*)(ws + XH_OFF);
        unsigned int*   cpart = (unsigned int*)(ws + CPART_OFF);
        unsigned int*   fpart = (unsigned int*)(ws + FPART_OFF);
        int*            ccurU = (int*)(ws + CCURU_OFF);
        int*            ccurI = (int*)(ws + CCURI_OFF);
        int*            fcurU = (int*)(ws + FCURU_OFF);
        int*            fcurI = (int*)(ws + FCURI_OFF);
        int*            ovfc  = (int*)(ws + OVFC_OFF);
        int2*           ovf   = (int2*)(ws + OVF_OFF);

        hipMemsetAsync(ws + CTR_OFF, 0, (size_t)CTR_LEN, stream);

        // K1: prep (z + scalars) fused with coarse user-side partition
        prep_partA0_kernel<<<PA_BLOCKS + PREP_BLOCKS, 256, 0, stream>>>(
            x, beta, du, di, scal, xh, u, i, ccurU, cpart, ovfc, ovf);
        // K2: fine user partition (XCD-local)
        partB_kernel<0><<<PB_BLOCKS, 256, 0, stream>>>(cpart, ccurU, fcurU, fpart, ovfc, ovf);
        // K3: user-side compute (LDS accumulate, write-once)
        compute_kernel<0><<<NFTOT, 256, 0, stream>>>(xh, scal, fcurU, fpart, out);
        // K4: coarse item partition (reuses cpart)
        partA_kernel<1><<<PA_BLOCKS, 256, 0, stream>>>(u, i, ccurI, cpart, ovfc, ovf);
        // K5: fine item partition
        partB_kernel<1><<<PB_BLOCKS, 256, 0, stream>>>(cpart, ccurI, fcurI, fpart, ovfc, ovf);
        // K6: item-side compute
        compute_kernel<1><<<NFTOT, 256, 0, stream>>>(xh, scal, fcurI, fpart, out);
        // K7: overflow fixup (normally ~0 entries)
        ovf2_kernel<<<64, 256, 0, stream>>>(x, scal, ovfc, ovf, out);
    } else {
        float* invn = (float*)ws;
        hipMemsetAsync(d_out, 0, (size_t)out_size * sizeof(float), stream);
        norm_kernel<<<(NR + 3) / 4, 256, 0, stream>>>(x, invn, NR);
        edge_kernel<<<(N_EDGES + 3) / 4, 256, 0, stream>>>(x, beta, du, di, u, i, invn, out);
    }
}

// Round 11
// 322.235 us; speedup vs baseline: 4.9776x; 4.9776x over previous
//
#include <hip/hip_runtime.h>
#include <math.h>

#define N_USERS 100000
#define N_ITEMS 50000
#define NR      150000
#define N_EDGES 2000000
#define D       64
#define EPS     1e-12f

#define UPAD 48      // user bucket capacity (deg ~ Poisson(20); P(>48) ~ 1e-8)
#define IPAD 64      // item bucket capacity (deg ~ Poisson(40); few rows spill -> ovf)
#define OVF_CAP 4096

#define NPART 8      // XCDs (blockIdx % 8 lands on XCD p under round-robin dispatch)
#define UCH (N_USERS / NPART)   // 12500
#define ICH (N_ITEMS / NPART)   // 6250
#define FILL_BLOCKS 2048        // 256 blocks per XCD partition

// ---------------- workspace layout (bytes) ----------------
// scal : float4[NR]          @ 0             2,400,000   {invn, rsd, beta, rsd*norm}
// xh   : ushort[NR*64] (z!)  @ 2,400,000    19,200,000
// cnt  : int[NR]             @ 21,600,000      600,000
// ubkt : u16[N_USERS*48]     @ 22,200,000     9,600,000
// ibkt : u32[N_ITEMS*64]     @ 31,800,000    12,800,000
// ovfc : int (+pad)          @ 44,600,000            8
// ovf  : int2[OVF_CAP]       @ 44,600,008       32,768
#define SCAL_OFF 0u
#define XH_OFF   2400000u
#define CNT_OFF  21600000u
#define UBKT_OFF 22200000u
#define IBKT_OFF 31800000u
#define OVFC_OFF 44600000u
#define OVF_OFF  44600008u
#define WS_MAIN  44632776u

__device__ __forceinline__ unsigned short f2bf(float v) {
    unsigned int b = __float_as_uint(v);
    b += 0x7FFFu + ((b >> 16) & 1u);          // round-to-nearest-even
    return (unsigned short)(b >> 16);
}
#define BF_LO(w) __uint_as_float((w) << 16)
#define BF_HI(w) __uint_as_float((w) & 0xFFFF0000u)

// ---------------------------------------------------------------------------
// Prep: xh[r] = bf16(z_r)  (pre-normalized row);
//       scal[r] = { invn, rsd, beta_or_0, rsd*norm }
// ---------------------------------------------------------------------------
__global__ void prep_kernel(const float* __restrict__ x,
                            const float* __restrict__ beta,
                            const float* __restrict__ du,
                            const float* __restrict__ di,
                            float4* __restrict__ scal,
                            unsigned short* __restrict__ xh) {
    int gid  = blockIdx.x * blockDim.x + threadIdx.x;
    int r    = gid >> 6;
    int lane = gid & 63;
    if (r >= NR) return;

    float v  = x[r * D + lane];
    float ss = v * v;
    #pragma unroll
    for (int m = 32; m >= 1; m >>= 1) ss += __shfl_xor(ss, m);

    float nrm  = fmaxf(sqrtf(ss), EPS);
    float invn = 1.0f / nrm;
    xh[r * D + lane] = f2bf(v * invn);        // store z, not x

    if (lane == 0) {
        float deg = (r < N_USERS) ? du[r] : di[r - N_USERS];
        float bb  = (r < N_USERS) ? beta[r] : 0.0f;
        float rsd = rsqrtf(deg);
        scal[r] = make_float4(invn, rsd, bb, rsd * nrm);
    }
}

// ---------------------------------------------------------------------------
// Round-6-proven single-pass XCD-partitioned bucket fill (NSUB=1).
// Blocks with blockIdx%8==p stream all edges (nt loads) but commit only rows
// in partition p; hot set (cnt slice + bucket slices ~2.9 MB) targets XCD p's
// private 4 MB L2.
// ---------------------------------------------------------------------------
__global__ void fillx_kernel(const int* __restrict__ u,
                             const int* __restrict__ i,
                             int* __restrict__ cnt,
                             unsigned short* __restrict__ ubkt,
                             unsigned int* __restrict__ ibkt,
                             int* __restrict__ ovfc,
                             int2* __restrict__ ovf) {
    int p   = blockIdx.x & (NPART - 1);
    int qb  = blockIdx.x >> 3;
    int tid = qb * blockDim.x + threadIdx.x;
    const int stride = (FILL_BLOCKS / NPART) * 256;

    int ulo = p * UCH, uhi = ulo + UCH;
    int ilo = p * ICH, ihi = ilo + ICH;

    for (int e = tid; e < N_EDGES; e += stride) {
        int uu = __builtin_nontemporal_load(u + e);
        int ii = __builtin_nontemporal_load(i + e);

        if (uu >= ulo && uu < uhi) {
            int s = atomicAdd(&cnt[uu], 1);
            if (s < UPAD) {
                ubkt[(size_t)uu * UPAD + s] = (unsigned short)ii;
            } else {
                int pp = atomicAdd(ovfc, 1);
                if (pp < OVF_CAP) ovf[pp] = make_int2(uu, N_USERS + ii);
            }
        }
        if (ii >= ilo && ii < ihi) {
            int s = atomicAdd(&cnt[N_USERS + ii], 1);
            if (s < IPAD) {
                ibkt[(size_t)ii * IPAD + s] = (unsigned int)uu;
            } else {
                int pp = atomicAdd(ovfc, 1);
                if (pp < OVF_CAP) ovf[pp] = make_int2(N_USERS + ii, uu);
            }
        }
    }
}

// ---------------------------------------------------------------------------
// Gather USER rows: wave per row, 8 neighbors/iter, chase-free.
// lane = (g = lane>>3 slot, q = lane&7 dim octet). z pre-normalized:
// acc += (4*sig*(1-sig)*c_nbr) * z_nbr ; out = acc * rsd_own.
// ---------------------------------------------------------------------------
__global__ void gatherU_kernel(const unsigned short* __restrict__ xh,
                               const float4* __restrict__ scal,
                               const int* __restrict__ cnt,
                               const unsigned short* __restrict__ ubkt,
                               float* __restrict__ out) {
    int gid  = blockIdx.x * blockDim.x + threadIdx.x;
    int r    = gid >> 6;
    int lane = gid & 63;
    if (r >= N_USERS) return;

    int g = lane >> 3;
    int q = lane & 7;

    float4 sc = scal[r];
    uint4 hs = *(const uint4*)(xh + (size_t)r * D + q * 8);
    float xs0 = BF_LO(hs.x), xs1 = BF_HI(hs.x);
    float xs2 = BF_LO(hs.y), xs3 = BF_HI(hs.y);
    float xs4 = BF_LO(hs.z), xs5 = BF_HI(hs.z);
    float xs6 = BF_LO(hs.w), xs7 = BF_HI(hs.w);

    int deg = cnt[r];
    if (deg > UPAD) deg = UPAD;
    int iters = (deg + 7) >> 3;

    float a0=0.f,a1=0.f,a2=0.f,a3=0.f,a4=0.f,a5=0.f,a6=0.f,a7=0.f;

    for (int it = 0; it < iters; ++it) {
        int idx = it * 8 + g;
        bool valid = (idx < deg);
        int nb = N_USERS + (int)ubkt[(size_t)r * UPAD + (valid ? idx : 0)];

        float4 so = scal[nb];
        uint4 ho = *(const uint4*)(xh + (size_t)nb * D + q * 8);
        float o0 = BF_LO(ho.x), o1 = BF_HI(ho.x);
        float o2 = BF_LO(ho.y), o3 = BF_HI(ho.y);
        float o4 = BF_LO(ho.z), o5 = BF_HI(ho.z);
        float o6 = BF_LO(ho.w), o7 = BF_HI(ho.w);

        float pd = xs0*o0 + xs1*o1 + xs2*o2 + xs3*o3
                 + xs4*o4 + xs5*o5 + xs6*o6 + xs7*o7;
        pd += __shfl_xor(pd, 1);
        pd += __shfl_xor(pd, 2);
        pd += __shfl_xor(pd, 4);             // cosine (z pre-scaled)

        float sv  = pd - sc.z;               // own (user) beta
        float sig = 1.0f / (1.0f + __expf(-sv));
        float t4  = 4.0f * sig * (1.0f - sig) * so.w;   // * c_nbr
        t4 = valid ? t4 : 0.0f;

        a0 = fmaf(t4, o0, a0); a1 = fmaf(t4, o1, a1);
        a2 = fmaf(t4, o2, a2); a3 = fmaf(t4, o3, a3);
        a4 = fmaf(t4, o4, a4); a5 = fmaf(t4, o5, a5);
        a6 = fmaf(t4, o6, a6); a7 = fmaf(t4, o7, a7);
    }

    #pragma unroll
    for (int m = 8; m <= 32; m <<= 1) {
        a0 += __shfl_xor(a0, m); a1 += __shfl_xor(a1, m);
        a2 += __shfl_xor(a2, m); a3 += __shfl_xor(a3, m);
        a4 += __shfl_xor(a4, m); a5 += __shfl_xor(a5, m);
        a6 += __shfl_xor(a6, m); a7 += __shfl_xor(a7, m);
    }

    if (g == 0) {
        float rsd = sc.y;
        float4* o4p = (float4*)(out + (size_t)r * D + q * 8);
        o4p[0] = make_float4(a0*rsd, a1*rsd, a2*rsd, a3*rsd);
        o4p[1] = make_float4(a4*rsd, a5*rsd, a6*rsd, a7*rsd);
    }
}

// ---------------------------------------------------------------------------
// Gather ITEM rows (neighbor = user row; beta from the neighbor).
// ---------------------------------------------------------------------------
__global__ void gatherI_kernel(const unsigned short* __restrict__ xh,
                               const float4* __restrict__ scal,
                               const int* __restrict__ cnt,
                               const unsigned int* __restrict__ ibkt,
                               float* __restrict__ out) {
    int gid  = blockIdx.x * blockDim.x + threadIdx.x;
    int ri   = gid >> 6;
    int lane = gid & 63;
    if (ri >= N_ITEMS) return;
    int r = N_USERS + ri;

    int g = lane >> 3;
    int q = lane & 7;

    float4 sc = scal[r];
    uint4 hs = *(const uint4*)(xh + (size_t)r * D + q * 8);
    float xs0 = BF_LO(hs.x), xs1 = BF_HI(hs.x);
    float xs2 = BF_LO(hs.y), xs3 = BF_HI(hs.y);
    float xs4 = BF_LO(hs.z), xs5 = BF_HI(hs.z);
    float xs6 = BF_LO(hs.w), xs7 = BF_HI(hs.w);

    int deg = cnt[r];
    if (deg > IPAD) deg = IPAD;
    int iters = (deg + 7) >> 3;

    float a0=0.f,a1=0.f,a2=0.f,a3=0.f,a4=0.f,a5=0.f,a6=0.f,a7=0.f;

    for (int it = 0; it < iters; ++it) {
        int idx = it * 8 + g;
        bool valid = (idx < deg);
        int nb = (int)ibkt[(size_t)ri * IPAD + (valid ? idx : 0)];

        float4 so = scal[nb];
        uint4 ho = *(const uint4*)(xh + (size_t)nb * D + q * 8);
        float o0 = BF_LO(ho.x), o1 = BF_HI(ho.x);
        float o2 = BF_LO(ho.y), o3 = BF_HI(ho.y);
        float o4 = BF_LO(ho.z), o5 = BF_HI(ho.z);
        float o6 = BF_LO(ho.w), o7 = BF_HI(ho.w);

        float pd = xs0*o0 + xs1*o1 + xs2*o2 + xs3*o3
                 + xs4*o4 + xs5*o5 + xs6*o6 + xs7*o7;
        pd += __shfl_xor(pd, 1);
        pd += __shfl_xor(pd, 2);
        pd += __shfl_xor(pd, 4);

        float sv  = pd - so.z;               // neighbor (user) beta
        float sig = 1.0f / (1.0f + __expf(-sv));
        float t4  = 4.0f * sig * (1.0f - sig) * so.w;   // * c_nbr
        t4 = valid ? t4 : 0.0f;

        a0 = fmaf(t4, o0, a0); a1 = fmaf(t4, o1, a1);
        a2 = fmaf(t4, o2, a2); a3 = fmaf(t4, o3, a3);
        a4 = fmaf(t4, o4, a4); a5 = fmaf(t4, o5, a5);
        a6 = fmaf(t4, o6, a6); a7 = fmaf(t4, o7, a7);
    }

    #pragma unroll
    for (int m = 8; m <= 32; m <<= 1) {
        a0 += __shfl_xor(a0, m); a1 += __shfl_xor(a1, m);
        a2 += __shfl_xor(a2, m); a3 += __shfl_xor(a3, m);
        a4 += __shfl_xor(a4, m); a5 += __shfl_xor(a5, m);
        a6 += __shfl_xor(a6, m); a7 += __shfl_xor(a7, m);
    }

    if (g == 0) {
        float rsd = sc.y;
        float4* o4p = (float4*)(out + (size_t)r * D + q * 8);
        o4p[0] = make_float4(a0*rsd, a1*rsd, a2*rsd, a3*rsd);
        o4p[1] = make_float4(a4*rsd, a5*rsd, a6*rsd, a7*rsd);
    }
}

// ---------------------------------------------------------------------------
// Overflow fixer: (own_row, nbr_row); recompute in fp32, atomic-add own row.
// ---------------------------------------------------------------------------
__global__ void ovf2_kernel(const float* __restrict__ x,
                            const float4* __restrict__ scal,
                            const int* __restrict__ ovfc,
                            const int2* __restrict__ ovf,
                            float* __restrict__ out) {
    int n = *ovfc;
    if (n > OVF_CAP) n = OVF_CAP;
    int gid  = blockIdx.x * blockDim.x + threadIdx.x;
    int wave = gid >> 6, lane = gid & 63;
    int nw   = (gridDim.x * blockDim.x) >> 6;

    for (int k = wave; k < n; k += nw) {
        int d  = ovf[k].x;
        int nb = ovf[k].y;
        float xd = x[(size_t)d * D + lane];
        float xn = x[(size_t)nb * D + lane];
        float pd = xd * xn;
        #pragma unroll
        for (int m = 32; m >= 1; m >>= 1) pd += __shfl_xor(pd, m);
        float4 sd = scal[d];
        float4 sn = scal[nb];
        float sv  = pd * sd.x * sn.x - (sd.z + sn.z);   // one side's beta is 0
        float sig = 1.0f / (1.0f + __expf(-sv));
        float w   = 4.0f * sig * (1.0f - sig) * sd.y * sn.y;
        atomicAdd(&out[(size_t)d * D + lane], w * xn);
    }
}

// ---------------------------------------------------------------------------
// Tier-D fallback (round-1 proven atomics) for small workspace.
// ---------------------------------------------------------------------------
__global__ void norm_kernel(const float* __restrict__ x,
                            float* __restrict__ invn, int nrows) {
    int gid  = blockIdx.x * blockDim.x + threadIdx.x;
    int wave = gid >> 6, lane = gid & 63;
    if (wave >= nrows) return;
    float v  = x[wave * D + lane];
    float ss = v * v;
    #pragma unroll
    for (int m = 32; m >= 1; m >>= 1) ss += __shfl_xor(ss, m);
    if (lane == 0) invn[wave] = 1.0f / fmaxf(sqrtf(ss), EPS);
}

__global__ void edge_kernel(const float* __restrict__ x,
                            const float* __restrict__ beta,
                            const float* __restrict__ du,
                            const float* __restrict__ di,
                            const int* __restrict__ u,
                            const int* __restrict__ i,
                            const float* __restrict__ invn,
                            float* __restrict__ out) {
    int gid  = blockIdx.x * blockDim.x + threadIdx.x;
    int wave = gid >> 6, lane = gid & 63;
    if (wave >= N_EDGES) return;
    int uu = u[wave], ii = i[wave];
    float xu = x[uu * D + lane];
    float xi = x[(N_USERS + ii) * D + lane];
    float p = xu * xi;
    #pragma unroll
    for (int m = 32; m >= 1; m >>= 1) p += __shfl_xor(p, m);
    float s   = p * invn[uu] * invn[N_USERS + ii] - beta[uu];
    float sig = 1.0f / (1.0f + __expf(-s));
    float w   = 4.0f * sig * (1.0f - sig) * rsqrtf(du[uu]) * rsqrtf(di[ii]);
    atomicAdd(&out[uu * D + lane],             w * xi);
    atomicAdd(&out[(N_USERS + ii) * D + lane], w * xu);
}

// ---------------------------------------------------------------------------
extern "C" void kernel_launch(void* const* d_in, const int* in_sizes, int n_in,
                              void* d_out, int out_size, void* d_ws, size_t ws_size,
                              hipStream_t stream) {
    const float* x    = (const float*)d_in[0];
    const float* beta = (const float*)d_in[1];
    const float* du   = (const float*)d_in[2];
    const float* di   = (const float*)d_in[3];
    const int*   u    = (const int*)d_in[4];
    const int*   i    = (const int*)d_in[5];
    float* out = (float*)d_out;
    char*  ws  = (char*)d_ws;

    if (ws_size >= (size_t)WS_MAIN) {
        float4*         scal = (float4*)(ws + SCAL_OFF);
        unsigned short* xh   = (unsigned short*)(ws + XH_OFF);
        int*            cnt  = (int*)(ws + CNT_OFF);
        unsigned short* ubkt = (unsigned short*)(ws + UBKT_OFF);
        unsigned int*   ibkt = (unsigned int*)(ws + IBKT_OFF);
        int*            ovfc = (int*)(ws + OVFC_OFF);
        int2*           ovf  = (int2*)(ws + OVF_OFF);

        hipMemsetAsync(cnt, 0, (size_t)NR * sizeof(int), stream);
        hipMemsetAsync(ovfc, 0, sizeof(int), stream);
        prep_kernel<<<(NR + 3) / 4, 256, 0, stream>>>(x, beta, du, di, scal, xh);
        fillx_kernel<<<FILL_BLOCKS, 256, 0, stream>>>(u, i, cnt, ubkt, ibkt, ovfc, ovf);
        gatherU_kernel<<<(N_USERS + 3) / 4, 256, 0, stream>>>(xh, scal, cnt, ubkt, out);
        gatherI_kernel<<<(N_ITEMS + 3) / 4, 256, 0, stream>>>(xh, scal, cnt, ibkt, out);
        ovf2_kernel<<<64, 256, 0, stream>>>(x, scal, ovfc, ovf, out);
    } else {
        float* invn = (float*)ws;
        hipMemsetAsync(d_out, 0, (size_t)out_size * sizeof(float), stream);
        norm_kernel<<<(NR + 3) / 4, 256, 0, stream>>>(x, invn, NR);
        edge_kernel<<<(N_EDGES + 3) / 4, 256, 0, stream>>>(x, beta, du, di, u, i, invn, out);
    }
}